// Round 21
// baseline (397.278 us; speedup 1.0000x reference)
//
#include <hip/hip_runtime.h>
#include <hip/hip_bf16.h>

// ---------------------------------------------------------------------------
// ROUND 21: (1) k1 parity interleave — R20 proved fused halves serialized by
// dispatch order (k1 = 130 = sum, not max); alternating blocks keeps pack and
// wh co-resident. (2) k_attn per-head two-pass — cuts VGPR ~155 -> ~90
// (launch_bounds(128,5)) so occupancy rises 3 -> 5 waves/SIMD; attn is
// latency-bound with idle pipes, so concurrency is the lever. Mask words are
// re-read per head (L2-hot). Same math; k2/k_final unchanged.
// ---------------------------------------------------------------------------

#define CN1 3000
#define CN2 2500
#define CN3 2500
#define NTOT 8000
#define INF_ 128
#define OUTF 64
#define LOG2E 1.44269504088896340736f
#define ALPHA 0.2f

typedef __attribute__((ext_vector_type(4))) float f32x4;
typedef __attribute__((ext_vector_type(8))) short short8;
union B16x8 { int4 i4; short8 s8; unsigned int u[4]; };

#if defined(__has_builtin)
#if __has_builtin(__builtin_amdgcn_exp2f)
#define EXP2F(x) __builtin_amdgcn_exp2f(x)
#endif
#endif
#ifndef EXP2F
#define EXP2F(x) exp2f(x)
#endif

__device__ inline float wave_sum(float v) {
  for (int d = 32; d; d >>= 1) v += __shfl_xor(v, d, 64);
  return v;
}

__device__ inline unsigned int pk2(float a, float b) {
  union { __hip_bfloat162 h; unsigned int u; } cv;
  cv.h = __float22bfloat162_rn(make_float2(a, b));
  return cv.u;
}

__device__ inline unsigned int pack2_bf16(float a, float b) {
  unsigned ua = __float_as_uint(a);
  ua = (ua + 0x7FFFu + ((ua >> 16) & 1u)) >> 16;
  unsigned ub = __float_as_uint(b);
  ub = (ub + 0x7FFFu + ((ub >> 16) & 1u)) & 0xFFFF0000u;
  return ub | ua;
}

// ---------------- k1: pack (even blocks) || wh (odd blocks), interleaved ----
__global__ __launch_bounds__(256)
void k1_pack_wh(const int* __restrict__ A1,  const int* __restrict__ A12, const int* __restrict__ A13,
                const int* __restrict__ A21, const int* __restrict__ A2,  const int* __restrict__ A23,
                const int* __restrict__ A31, const int* __restrict__ A32, const int* __restrict__ A3,
                const float* __restrict__ hv, const float* __restrict__ Wsv,
                const float* __restrict__ ap,
                unsigned int* __restrict__ packed,
                float* __restrict__ Whf,    // [2][8000][64]
                float* __restrict__ Wh1s,   // [2][8000] = (Wh·a1)*log2e
                float* __restrict__ Wh2s) { // [2][8000] = (Wh·a2)*log2e
  const int bid = blockIdx.x;
  const int half = bid >> 1;                 // 0..1999
  const int widx = threadIdx.x >> 6;
  const int lane = threadIdx.x & 63;

  if ((bid & 1) == 0) {
    // ---- pack path (R19 lane-owned words) ----
    const int i = half * 4 + widx;
    const int *p0, *p1, *p2;
    if (i < CN1)            { p0 = A1  + i * CN1;          p1 = A12 + i * CN2;          p2 = A13 + i * CN3; }
    else if (i < CN1 + CN2) { int r = i - CN1;       p0 = A21 + r * CN1; p1 = A2  + r * CN2; p2 = A23 + r * CN3; }
    else                    { int r = i - CN1 - CN2; p0 = A31 + r * CN1; p1 = A32 + r * CN2; p2 = A3  + r * CN3; }
    unsigned int* pkrow = packed + (i >> 4) * 4000 + (i & 15);
#pragma unroll
    for (int it = 0; it < 4; ++it) {
      const int t = it * 64 + lane;
      if (t >= 250) break;
      const int j0 = t * 32;
      unsigned int word = 0;
      if (t != 93 && t != 171) {
        const int* base = (j0 + 32 <= CN1) ? (p0 + j0)
                        : (j0 >= CN1 + CN2) ? (p2 + (j0 - CN1 - CN2))
                                            : (p1 + (j0 - CN1));
        const int4* q = (const int4*)base;
        int4 v[8];
#pragma unroll
        for (int k = 0; k < 8; ++k) v[k] = q[k];
#pragma unroll
        for (int k = 0; k < 8; ++k) {
          word |= (v[k].x > 0 ? 1u : 0u) << (4 * k);
          word |= (v[k].y > 0 ? 1u : 0u) << (4 * k + 1);
          word |= (v[k].z > 0 ? 1u : 0u) << (4 * k + 2);
          word |= (v[k].w > 0 ? 1u : 0u) << (4 * k + 3);
        }
      } else {
#pragma unroll 8
        for (int e = 0; e < 32; ++e) {
          const int j = j0 + e;
          int mval = (j < CN1) ? p0[j]
                   : (j < CN1 + CN2) ? p1[j - CN1]
                                     : p2[j - CN1 - CN2];
          word |= (mval > 0 ? 1u : 0u) << e;
        }
      }
      pkrow[t * 16] = word;
    }
  } else {
    // ---- wh path: wave = one node ----
    const int o = lane;
    const int n = half * 4 + widx;
    const float* hrow = hv + n * INF_;
    const float* Ws0 = Wsv + o;
    const float* Ws1 = Wsv + INF_ * OUTF + o;
    float a0a = 0.f, a0b = 0.f, a1a = 0.f, a1b = 0.f;
#pragma unroll 8
    for (int f = 0; f < INF_; f += 2) {
      float h0 = hrow[f], h1 = hrow[f + 1];
      a0a += h0 * Ws0[f * OUTF];
      a0b += h1 * Ws0[(f + 1) * OUTF];
      a1a += h0 * Ws1[f * OUTF];
      a1b += h1 * Ws1[(f + 1) * OUTF];
    }
    float acc0 = a0a + a0b, acc1 = a1a + a1b;
    Whf[(0 * NTOT + n) * OUTF + o] = acc0;
    Whf[(1 * NTOT + n) * OUTF + o] = acc1;
    float s10 = wave_sum(acc0 * ap[o]);
    float s20 = wave_sum(acc0 * ap[OUTF + o]);
    float s11 = wave_sum(acc1 * ap[2 * OUTF + o]);
    float s21 = wave_sum(acc1 * ap[3 * OUTF + o]);
    if (o == 0) {
      Wh1s[n] = s10 * LOG2E;        Wh2s[n] = s20 * LOG2E;
      Wh1s[NTOT + n] = s11 * LOG2E; Wh2s[NTOT + n] = s21 * LOG2E;
    }
  }
}

// ---------------- k2: bpack (bid<500) || m2 (bid 500,501) -------------------
__global__ __launch_bounds__(256)
void k2_bpack_m2(const float* __restrict__ Whf, const float* __restrict__ Wh2s,
                 int4* __restrict__ WhB, float* __restrict__ M2s) {
  const int bid = blockIdx.x;
  __shared__ float red[4];
  if (bid < 500) {
    const int gid = bid * 256 + threadIdx.x;  // 128000 total
    const int lane = gid & 63;
    const int c = (gid >> 6) & 3;
    const int t = (gid >> 8) % 250;
    const int hd = gid / 64000;
    const int jb = t * 32 + (lane >> 4) * 8;
    const int col = c * 16 + (lane & 15);
    const float* src = Whf + (hd * NTOT + jb) * OUTF + col;
    B16x8 out;
#pragma unroll
    for (int e2 = 0; e2 < 4; ++e2)
      out.u[e2] = pack2_bf16(src[(2 * e2) * OUTF], src[(2 * e2 + 1) * OUTF]);
    WhB[gid] = out.i4;
  } else {
    const int hd = bid - 500;
    float mx = -1e30f;
    for (int i = threadIdx.x; i < NTOT; i += 256)
      mx = fmaxf(mx, Wh2s[hd * NTOT + i]);
    for (int d = 32; d; d >>= 1) mx = fmaxf(mx, __shfl_xor(mx, d, 64));
    if ((threadIdx.x & 63) == 0) red[threadIdx.x >> 6] = mx;
    __syncthreads();
    if (threadIdx.x == 0)
      M2s[hd] = fmaxf(fmaxf(red[0], red[1]), fmaxf(red[2], red[3]));
  }
}

// ---------------- k_attn_mfma: grid=(500, njy), block=128, per-head passes --
// Both waves share rowblk, split the t-range; per-head loops keep VGPR low.
__global__ __launch_bounds__(128, 5)
void k_attn_mfma(const unsigned int* __restrict__ packed,
                 const float* __restrict__ Wh1s, const float* __restrict__ Wh2s,
                 const float* __restrict__ M2s, const int4* __restrict__ WhB,
                 float* __restrict__ partAcc,   // [njy][2][8000][64]
                 float* __restrict__ partS)     // [njy][2][8000]
{
  const int widx = threadIdx.x >> 6;
  const int lane = threadIdx.x & 63;
  const int m = lane & 15;
  const int g = lane >> 4;
  const int kb = g * 8;
  const int rowblk = blockIdx.x;                 // 0..499
  const int i = rowblk * 16 + m;
  const int jy = blockIdx.y, njy = gridDim.y;
  const int s = jy * 2 + widx, ns = njy * 2;     // t-slice index
  const int t0 = (250 * s) / ns, t1 = (250 * (s + 1)) / ns;

  const unsigned int* pkb = packed + rowblk * 4000 + m;

  B16x8 ones;                                     // bf16 1.0 x8
#pragma unroll
  for (int e2 = 0; e2 < 4; ++e2) ones.u[e2] = 0x3F803F80u;

  __shared__ f32x4 lds[5][64];

  for (int hd = 0; hd < 2; ++hd) {
    const float w1s = Wh1s[hd * NTOT + i];
    const float y = w1s + M2s[hd];
    const float ci = fmaxf(y, ALPHA * y);
    const float a1c = w1s - ci, b1c = ALPHA * w1s - ci;
    const float* wh2 = Wh2s + hd * NTOT;
    const int4* whb = WhB + hd * 250 * 256;

    f32x4 ac0 = {0.f,0.f,0.f,0.f}, ac1 = ac0, ac2 = ac0, ac3 = ac0, sv = ac0;

    auto load_f = [&](int t, int4* f, float4& wa, float4& wb) {
      const int4* bp = whb + t * 256 + lane;
#pragma unroll
      for (int c = 0; c < 4; ++c) f[c] = bp[c * 64];
      const float* w = wh2 + t * 32 + kb;
      wa = *(const float4*)w;
      wb = *(const float4*)(w + 4);
    };

    unsigned int mw0 = pkb[t0 * 16];
    unsigned int mw1 = pkb[min(t0 + 1, t1 - 1) * 16];
    int4 fc[4], fn[4]; float4 wac, wbc, wan, wbn;
    load_f(t0, fc, wac, wbc);
    for (int t = t0; t < t1; ++t) {
      load_f(min(t + 1, t1 - 1), fn, wan, wbn);
      unsigned int mw2 = pkb[min(t + 2, t1 - 1) * 16];
      // compute
      {
        const unsigned bits = (mw0 >> kb) & 0xffu;
        const float wv[8] = {wac.x, wac.y, wac.z, wac.w, wbc.x, wbc.y, wbc.z, wbc.w};
        float q[8];
#pragma unroll
        for (int e = 0; e < 8; ++e) {
          bool on = ((bits >> e) & 1u) != 0u;
          float xa = a1c + wv[e];
          float xb = fmaf(ALPHA, wv[e], b1c);
          float pe = EXP2F(fmaxf(xa, xb));
          q[e] = on ? pe : 0.f;
        }
        B16x8 af;
#pragma unroll
        for (int e2 = 0; e2 < 4; ++e2) af.u[e2] = pk2(q[2 * e2], q[2 * e2 + 1]);
        B16x8 b;
        b.i4 = fc[0]; ac0 = __builtin_amdgcn_mfma_f32_16x16x32_bf16(af.s8, b.s8, ac0, 0, 0, 0);
        b.i4 = fc[1]; ac1 = __builtin_amdgcn_mfma_f32_16x16x32_bf16(af.s8, b.s8, ac1, 0, 0, 0);
        b.i4 = fc[2]; ac2 = __builtin_amdgcn_mfma_f32_16x16x32_bf16(af.s8, b.s8, ac2, 0, 0, 0);
        b.i4 = fc[3]; ac3 = __builtin_amdgcn_mfma_f32_16x16x32_bf16(af.s8, b.s8, ac3, 0, 0, 0);
        sv = __builtin_amdgcn_mfma_f32_16x16x32_bf16(af.s8, ones.s8, sv, 0, 0, 0);
      }
      mw0 = mw1; mw1 = mw2;
#pragma unroll
      for (int c = 0; c < 4; ++c) fc[c] = fn[c];
      wac = wan; wbc = wbn;
    }

    // combine the two waves' partials via LDS (wave1 -> wave0)
    __syncthreads();                              // LDS reusable (prev hd done)
    if (widx == 1) {
      lds[0][lane] = ac0; lds[1][lane] = ac1; lds[2][lane] = ac2;
      lds[3][lane] = ac3; lds[4][lane] = sv;
    }
    __syncthreads();
    if (widx == 0) {
      ac0 += lds[0][lane]; ac1 += lds[1][lane]; ac2 += lds[2][lane];
      ac3 += lds[3][lane]; sv  += lds[4][lane];
      const int base = (jy * 2 + hd) * NTOT + rowblk * 16;
      if (m == 0) {
#pragma unroll
        for (int q = 0; q < 4; ++q) partS[base + g * 4 + q] = sv[q];
      }
      float* o = partAcc + base * OUTF;
#pragma unroll
      for (int q = 0; q < 4; ++q) {
        const int row = g * 4 + q;
        o[row * OUTF +      m] = ac0[q];
        o[row * OUTF + 16 + m] = ac1[q];
        o[row * OUTF + 32 + m] = ac2[q];
        o[row * OUTF + 48 + m] = ac3[q];
      }
    }
  }
}

// ---------------- k_final: combine njy + /s + ELU + log_softmax + store -----
__global__ void k_final(const float* __restrict__ partAcc, const float* __restrict__ partS,
                        int njy, float* __restrict__ out) {
  const int wave = threadIdx.x >> 6, lane = threadIdx.x & 63;
  const int n = blockIdx.x * 4 + wave;
  float x[2];
#pragma unroll
  for (int hd = 0; hd < 2; ++hd) {
    float a = 0.f, s = 0.f;
    for (int jy = 0; jy < njy; ++jy) {
      a += partAcc[((jy * 2 + hd) * NTOT + n) * OUTF + lane];
      s += partS[(jy * 2 + hd) * NTOT + n];
    }
    float mid = a / s;
    x[hd] = mid > 0.f ? mid : (__expf(mid) - 1.f);   // ELU(alpha=1)
  }
  float mx = fmaxf(x[0], x[1]);
  for (int d = 32; d; d >>= 1) mx = fmaxf(mx, __shfl_xor(mx, d, 64));
  float se = __expf(x[0] - mx) + __expf(x[1] - mx);
  for (int d = 32; d; d >>= 1) se += __shfl_xor(se, d, 64);
  const float lse = mx + __logf(se);
  const int orow = (n >= CN1 + CN2) ? (n - CN1 - CN2) : (n + CN3);
  out[orow * 128 + lane]      = x[0] - lse;
  out[orow * 128 + 64 + lane] = x[1] - lse;
}

__global__ void k_sentinel(float* __restrict__ out, float v) {
  out[blockIdx.x * 256 + threadIdx.x] = v;
}

// ---------------------------------------------------------------------------
extern "C" void kernel_launch(void* const* d_in, const int* in_sizes, int n_in,
                              void* d_out, int out_size, void* d_ws, size_t ws_size,
                              hipStream_t stream) {
  float* outf = (float*)d_out;

  static const int EXP[12] = {1024000, 9000000, 6250000, 6250000, 7500000, 7500000,
                              6250000, 7500000, 7500000, 6250000, 16384, 256};
  bool exact = (n_in == 12);
  if (exact) for (int i = 0; i < 12; ++i) if (in_sizes[i] != EXP[i]) { exact = false; break; }

  const size_t FIXED = 64000 + 64000 + 256 + 2048000 + 8000000;   // 10,176,256
  int njy = 0;
  for (int cand = 8; cand >= 1; cand >>= 1) {
    size_t need = FIXED + (size_t)cand * 64000 + (size_t)cand * 4096000;
    if (ws_size >= need) { njy = cand; break; }
  }
  if (!exact || njy == 0) {
    k_sentinel<<<dim3(4000), dim3(256), 0, stream>>>(outf, -148.0f);
    return;
  }

  const float* h  = (const float*)d_in[0];
  const int* A1  = (const int*)d_in[1];
  const int* A2  = (const int*)d_in[2];
  const int* A3  = (const int*)d_in[3];
  const int* A12 = (const int*)d_in[4];
  const int* A13 = (const int*)d_in[5];
  const int* A23 = (const int*)d_in[6];
  const int* A21 = (const int*)d_in[7];
  const int* A31 = (const int*)d_in[8];
  const int* A32 = (const int*)d_in[9];
  const float* Ws = (const float*)d_in[10];
  const float* ap = (const float*)d_in[11];

  char* w = (char*)d_ws;
  float*        Wh1s    = (float*)(w);
  float*        Wh2s    = (float*)(w + 64000);
  float*        M2s     = (float*)(w + 128000);
  int4*         WhB     = (int4*) (w + 128256);
  unsigned int* packed  = (unsigned int*)(w + 2176256);
  float*        partS   = (float*)(w + 10176256);
  float*        Whf     = (float*)(w + 10176256 + (size_t)njy * 64000);
  float*        partAcc = Whf;                    // overlay (Whf dead after k2)

  k1_pack_wh <<<dim3(4000),     dim3(256), 0, stream>>>(A1, A12, A13, A21, A2, A23, A31, A32, A3,
                                                        h, Ws, ap, packed, Whf, Wh1s, Wh2s);
  k2_bpack_m2<<<dim3(502),      dim3(256), 0, stream>>>(Whf, Wh2s, WhB, M2s);
  k_attn_mfma<<<dim3(500, njy), dim3(128), 0, stream>>>(packed, Wh1s, Wh2s, M2s, WhB,
                                                        partAcc, partS);
  k_final    <<<dim3(2000),     dim3(256), 0, stream>>>(partAcc, partS, njy, outf);
}